// Round 1
// baseline (146.891 us; speedup 1.0000x reference)
//
#include <hip/hip_runtime.h>

#define N_GENERA 4096
#define N_RANKS 6
#define N_GROUPS 256
#define NCH 7                         // 6 ranks + identity channel
#define SEG_SZ (N_RANKS * N_GROUPS)   // 1536
#define EXT_SZ (SEG_SZ + N_GENERA)    // 5632 floats = 22.5 KB
#define NF (N_GENERA * NCH)           // 28672 output floats per b
#define NF4 (NF / 4)                  // 7168 float4 per b

typedef float f32x4 __attribute__((ext_vector_type(4)));

// ws layout:
//   pk   [4096][8] ushort @ 0      (64 KB)  packed ext-addresses per genus:
//                                           pk[i][r] = r*256 + lab[r][i], r<6
//   sidx [NF]      short  @ 65536  (56 KB)  output-float -> ext[] index map
#define WS_PK_OFF   0
#define WS_SIDX_OFF 65536

// ---------- Kernel 0: prep = pk table (blocks 0..15) + sidx map (blocks 16..127) ----------
__global__ __launch_bounds__(256) void prep_kernel(
    const int* __restrict__ labels,
    uint* __restrict__ pk,      // viewed as uint4 per genus
    short* __restrict__ sidx)   // [NF]
{
    const int t = threadIdx.x;

    if (blockIdx.x < 16) {
        const int i = blockIdx.x * 256 + t;   // genus
        const int l0 = labels[0 * N_GENERA + i];
        const int l1 = labels[1 * N_GENERA + i];
        const int l2 = labels[2 * N_GENERA + i];
        const int l3 = labels[3 * N_GENERA + i];
        const int l4 = labels[4 * N_GENERA + i];
        const int l5 = labels[5 * N_GENERA + i];
        uint4 w;
        w.x = (uint)(l0)        | ((uint)(256  + l1) << 16);
        w.y = (uint)(512 + l2)  | ((uint)(768  + l3) << 16);
        w.z = (uint)(1024 + l4) | ((uint)(1280 + l5) << 16);
        w.w = 0u;
        reinterpret_cast<uint4*>(pk)[i] = w;
    } else {
        // sidx: output-float -> ext[]-index map (batch-independent)
        const int f = (blockIdx.x - 16) * 256 + t;   // < NF
        const int j = f / NCH;
        const int ch = f - j * NCH;
        int v;
        if (ch < N_RANKS)
            v = ch * N_GROUPS + labels[ch * N_GENERA + j];
        else
            v = SEG_SZ + j;               // identity channel -> F slot
        sidx[f] = (short)v;
    }
}

// ---------- Kernel 1: fused seg-scatter + gather, one block per b, 512 threads ----------
// LDS ext[] = { seg[6][256] | Frow[4096] } (22.5 KB).
// Phase A: stage Frow global->reg->LDS; scatter each thread's 8 register F
//          values into seg[] via ds_add_f32 (uniform work, no divergence,
//          no LDS reads, no CSR).
// Phase B: thread owns output float4s: coalesced short4 sidx read, 4 LDS
//          gathers, 1 contiguous nontemporal float4 store. Two barriers total.
__global__ __launch_bounds__(512) void fused_kernel(
    const float* __restrict__ F,
    const uint* __restrict__ pk,
    const short* __restrict__ sidx,
    float* __restrict__ out)
{
    __shared__ float ext[EXT_SZ];
    const int b = blockIdx.x;
    const int t = threadIdx.x;

    // zero seg region (1536 = 3*512)
    ext[t]        = 0.f;
    ext[t + 512]  = 0.f;
    ext[t + 1024] = 0.f;

    // stage Frow into regs + ext[SEG_SZ..): thread t owns genera
    // {4t..4t+3} (f0) and {2048+4t..2048+4t+3} (f1)
    const f32x4* Fv = reinterpret_cast<const f32x4*>(F + (size_t)b * N_GENERA);
    const f32x4 f0 = __builtin_nontemporal_load(Fv + t);
    const f32x4 f1 = __builtin_nontemporal_load(Fv + t + 512);
    f32x4* Flv = reinterpret_cast<f32x4*>(ext + SEG_SZ);
    Flv[t]       = f0;
    Flv[t + 512] = f1;

    __syncthreads();   // seg zeroed before atomics (stage writes also in flight)

    // Phase A: register->LDS scatter, 6 ds_add_f32 per genus, 8 genera/thread
    const uint4* pk4 = reinterpret_cast<const uint4*>(pk);
    #pragma unroll
    for (int u = 0; u < 4; ++u) {
        const uint4 p = pk4[4 * t + u];
        const float fv = f0[u];
        atomicAdd(&ext[p.x & 0xffffu], fv);
        atomicAdd(&ext[p.x >> 16],     fv);
        atomicAdd(&ext[p.y & 0xffffu], fv);
        atomicAdd(&ext[p.y >> 16],     fv);
        atomicAdd(&ext[p.z & 0xffffu], fv);
        atomicAdd(&ext[p.z >> 16],     fv);
    }
    #pragma unroll
    for (int u = 0; u < 4; ++u) {
        const uint4 p = pk4[2048 + 4 * t + u];
        const float fv = f1[u];
        atomicAdd(&ext[p.x & 0xffffu], fv);
        atomicAdd(&ext[p.x >> 16],     fv);
        atomicAdd(&ext[p.y & 0xffffu], fv);
        atomicAdd(&ext[p.y >> 16],     fv);
        atomicAdd(&ext[p.z & 0xffffu], fv);
        atomicAdd(&ext[p.z >> 16],     fv);
    }
    __syncthreads();

    // Phase B: 14 output float4 per thread, lanes contiguous per store
    f32x4* __restrict__ op = reinterpret_cast<f32x4*>(out) + (size_t)b * NF4;
    #pragma unroll
    for (int kk = 0; kk < 14; ++kk) {
        const int q = kk * 512 + t;
        short4 s4 = *reinterpret_cast<const short4*>(sidx + q * 4);
        f32x4 v;
        v[0] = ext[s4.x];
        v[1] = ext[s4.y];
        v[2] = ext[s4.z];
        v[3] = ext[s4.w];
        __builtin_nontemporal_store(v, op + q);
    }
}

extern "C" void kernel_launch(void* const* d_in, const int* in_sizes, int n_in,
                              void* d_out, int out_size, void* d_ws, size_t ws_size,
                              hipStream_t stream) {
    const float* F      = (const float*)d_in[0];
    const int*   labels = (const int*)d_in[1];
    float*       out    = (float*)d_out;

    const int B = in_sizes[0] / N_GENERA;  // 1024
    char* ws = (char*)d_ws;
    uint*  pk   = (uint*)(ws + WS_PK_OFF);
    short* sidx = (short*)(ws + WS_SIDX_OFF);

    const int sidx_blocks = NF / 256;   // 112
    prep_kernel<<<dim3(16 + sidx_blocks), dim3(256), 0, stream>>>(labels, pk, sidx);
    fused_kernel<<<dim3(B), dim3(512), 0, stream>>>(F, pk, sidx, out);
}

// Round 2
// 43.051 us; speedup vs baseline: 3.4121x; 3.4121x over previous
//
#include <hip/hip_runtime.h>

#define N_GENERA 4096
#define N_RANKS 6
#define N_GROUPS 256
#define NCH 7                         // 6 ranks + identity channel
#define SEG_SZ (N_RANKS * N_GROUPS)   // 1536
#define EXT_SZ (SEG_SZ + N_GENERA)    // 5632 pairs = 45 KB as float2
#define NF (N_GENERA * NCH)           // 28672 output floats per b
#define NF4 (NF / 4)                  // 7168 float4 per b

typedef float f32x4 __attribute__((ext_vector_type(4)));

// ws layout:
//   idx  [6][4096] int   @ 0        (96 KB)
//   offs [6][260]  int   @ 98304    (6.1 KB)
//   sidx [NF]      short @ 104704   (56 KB)
#define WS_IDX_OFF  0
#define WS_OFFS_OFF 98304
#define WS_SIDX_OFF 104704

// ---------- Kernel 0: prep = per-rank CSR (blocks 0..5) + sidx map (blocks 6..117) ----------
__global__ __launch_bounds__(256) void prep_kernel(
    const int* __restrict__ labels,
    int* __restrict__ idx,      // [R][N_GENERA]
    int* __restrict__ offs,     // [R][260]
    short* __restrict__ sidx)   // [NF]
{
    const int t = threadIdx.x;

    if (blockIdx.x < N_RANKS) {
        const int r = blockIdx.x;
        const int* __restrict__ lab = labels + r * N_GENERA;

        __shared__ int cnt[N_GROUPS];
        __shared__ int scan[N_GROUPS];
        __shared__ int cur[N_GROUPS];

        cnt[t] = 0;
        __syncthreads();
        for (int i = t; i < N_GENERA; i += 256)
            atomicAdd(&cnt[lab[i]], 1);   // int atomics, build-once: cheap enough
        __syncthreads();

        int v = cnt[t];
        scan[t] = v;
        __syncthreads();
        #pragma unroll
        for (int s = 1; s < 256; s <<= 1) {
            int add = (t >= s) ? scan[t - s] : 0;
            __syncthreads();
            scan[t] += add;
            __syncthreads();
        }
        int start = scan[t] - v;          // exclusive prefix
        cur[t] = start;
        offs[r * 260 + t] = start;
        if (t == 0) offs[r * 260 + 256] = N_GENERA;
        __syncthreads();
        for (int i = t; i < N_GENERA; i += 256) {
            int p = atomicAdd(&cur[lab[i]], 1);
            idx[r * N_GENERA + p] = i;
        }
    } else {
        // sidx: output-float -> ext[]-index map (batch-independent)
        const int f = (blockIdx.x - N_RANKS) * 256 + t;   // < NF
        const int j = f / NCH;
        const int ch = f - j * NCH;
        int v;
        if (ch < N_RANKS)
            v = ch * N_GROUPS + labels[ch * N_GENERA + j];
        else
            v = SEG_SZ + j;               // identity channel -> F slot
        sidx[f] = (short)v;
    }
}

// ---------- Kernel 1: fused CSR-seg + gather, TWO batch rows per block ----------
// LDS ext2[] = { seg[1536] | Frow[4096] } of float2 = {val_b0, val_b1} (45 KB).
// Amortizes every scattered LDS access across 2 batch rows: one ds_read_b64
// serves two output floats. sidx/CSR maps are batch-independent.
// Phase A: stage 2 F rows pair-interleaved; each thread serially sums its
//          3 CSR (rank,group) lists (both b's per ds_read_b64, no atomics).
// Phase B: coalesced short4 sidx read, 4 ds_read_b64 gathers, 2 contiguous
//          nontemporal float4 stores (one per b). Two barriers total.
__global__ __launch_bounds__(512) void fused_kernel(
    const float* __restrict__ F,
    const int* __restrict__ idx,
    const int* __restrict__ offs,
    const short* __restrict__ sidx,
    float* __restrict__ out)
{
    __shared__ float2 ext2[EXT_SZ];
    const int b0 = blockIdx.x * 2;
    const int t = threadIdx.x;

    // zero seg region (1536 pairs = 3*512)
    const float2 z2 = {0.f, 0.f};
    ext2[t] = z2; ext2[t + 512] = z2; ext2[t + 1024] = z2;

    // stage 2 F rows pair-interleaved into ext2[SEG_SZ..)
    const f32x4* Fv0 = reinterpret_cast<const f32x4*>(F + (size_t)b0 * N_GENERA);
    const f32x4* Fv1 = reinterpret_cast<const f32x4*>(F + (size_t)(b0 + 1) * N_GENERA);
    f32x4* Flv = reinterpret_cast<f32x4*>(ext2 + SEG_SZ);
    #pragma unroll
    for (int k = 0; k < 2; ++k) {
        const f32x4 a = __builtin_nontemporal_load(Fv0 + t + k * 512);
        const f32x4 c = __builtin_nontemporal_load(Fv1 + t + k * 512);
        f32x4 lo, hi;
        lo[0] = a[0]; lo[1] = c[0]; lo[2] = a[1]; lo[3] = c[1];
        hi[0] = a[2]; hi[1] = c[2]; hi[2] = a[3]; hi[3] = c[3];
        Flv[2 * (t + k * 512)]     = lo;
        Flv[2 * (t + k * 512) + 1] = hi;
    }
    __syncthreads();

    // Phase A: CSR segment sums for both b's, 3 (r,g) items per thread
    const float2* __restrict__ Fl2 = ext2 + SEG_SZ;
    #pragma unroll
    for (int w = 0; w < 3; ++w) {
        const int item = t + w * 512;
        const int r = item >> 8;
        const int g = item & 255;
        const int e = offs[r * 260 + g + 1];   // g==255 -> offs[r][256]==4096
        int k = offs[r * 260 + g];
        const int* __restrict__ ip = idx + r * N_GENERA;
        float sa = 0.f, sb = 0.f;
        for (; k + 4 <= e; k += 4) {
            int i0 = ip[k], i1 = ip[k + 1], i2 = ip[k + 2], i3 = ip[k + 3];
            float2 v0 = Fl2[i0], v1 = Fl2[i1], v2 = Fl2[i2], v3 = Fl2[i3];
            sa += (v0.x + v1.x) + (v2.x + v3.x);
            sb += (v0.y + v1.y) + (v2.y + v3.y);
        }
        for (; k < e; ++k) {
            float2 v = Fl2[ip[k]];
            sa += v.x; sb += v.y;
        }
        float2 sp; sp.x = sa; sp.y = sb;
        ext2[item] = sp;   // seg region; disjoint from F region being read
    }
    __syncthreads();

    // Phase B: 14 output float4 per b per thread, lanes contiguous per store
    f32x4* __restrict__ op0 = reinterpret_cast<f32x4*>(out) + (size_t)b0 * NF4;
    f32x4* __restrict__ op1 = op0 + NF4;
    #pragma unroll
    for (int kk = 0; kk < 14; ++kk) {
        const int q = kk * 512 + t;
        short4 s4 = *reinterpret_cast<const short4*>(sidx + q * 4);
        float2 p0 = ext2[s4.x];
        float2 p1 = ext2[s4.y];
        float2 p2 = ext2[s4.z];
        float2 p3 = ext2[s4.w];
        f32x4 va, vb;
        va[0] = p0.x; va[1] = p1.x; va[2] = p2.x; va[3] = p3.x;
        vb[0] = p0.y; vb[1] = p1.y; vb[2] = p2.y; vb[3] = p3.y;
        __builtin_nontemporal_store(va, op0 + q);
        __builtin_nontemporal_store(vb, op1 + q);
    }
}

extern "C" void kernel_launch(void* const* d_in, const int* in_sizes, int n_in,
                              void* d_out, int out_size, void* d_ws, size_t ws_size,
                              hipStream_t stream) {
    const float* F      = (const float*)d_in[0];
    const int*   labels = (const int*)d_in[1];
    float*       out    = (float*)d_out;

    const int B = in_sizes[0] / N_GENERA;  // 1024
    char* ws = (char*)d_ws;
    int*   idx  = (int*)(ws + WS_IDX_OFF);
    int*   offs = (int*)(ws + WS_OFFS_OFF);
    short* sidx = (short*)(ws + WS_SIDX_OFF);

    const int sidx_blocks = NF / 256;   // 112
    prep_kernel<<<dim3(N_RANKS + sidx_blocks), dim3(256), 0, stream>>>(labels, idx, offs, sidx);
    fused_kernel<<<dim3(B / 2), dim3(512), 0, stream>>>(F, idx, offs, sidx, out);
}